// Round 11
// baseline (906.335 us; speedup 1.0000x reference)
//
#include <hip/hip_runtime.h>

#define NEG_SLOPE 0.2f

typedef __attribute__((ext_vector_type(4))) float floatx4;
typedef __attribute__((ext_vector_type(8))) short shortx8;

__device__ __forceinline__ unsigned short f2bf(float f) {
  union { float f; unsigned int u; } v;
  v.f = f;
  unsigned int r = (v.u + 0x7FFFu + ((v.u >> 16) & 1u)) >> 16;
  return (unsigned short)r;
}
__device__ __forceinline__ float bf2f(unsigned short u) {
  union { unsigned int u; float f; } v;
  v.u = (unsigned int)u << 16;
  return v.f;
}
__device__ __forceinline__ void store_out(float* p, float v) { *p = v; }
__device__ __forceinline__ void store_out(unsigned short* p, float v) { *p = f2bf(v); }

// async global->LDS, 16B per lane, LDS dest = wave-uniform base + lane*16
__device__ __forceinline__ void gload_lds16(const unsigned short* g, unsigned short* l) {
  __builtin_amdgcn_global_load_lds(
      (const __attribute__((address_space(1))) void*)(g),
      (__attribute__((address_space(3))) void*)(l), 16, 0, 0);
}

// ---------------- edge index width detection (int32 vs int64) ----------------
__device__ __forceinline__ int load_edge(const void* ei, long idx, int is64) {
  if (is64) return (int)((const long long*)ei)[idx];
  return ((const int*)ei)[idx];
}

__global__ void detect64_kernel(const unsigned int* __restrict__ p, int* __restrict__ flag) {
  int is64 = 1;
  for (int i = 0; i < 32; ++i)
    if (p[2 * i + 1] != 0u) is64 = 0;
  *flag = is64;
}

// ---------------- CSR build ----------------
__global__ void init_cnt_kernel(int* __restrict__ cnt, int n) {
  int i = blockIdx.x * blockDim.x + threadIdx.x;
  if (i < n) cnt[i] = 1;  // self-loop
}

__global__ void count_kernel(const void* __restrict__ ei, const int* __restrict__ flag, int E,
                             int* __restrict__ cnt) {
  int e = blockIdx.x * blockDim.x + threadIdx.x;
  if (e >= E) return;
  int is64 = *flag;
  int d = load_edge(ei, (long)E + e, is64);
  atomicAdd(&cnt[d], 1);
}

__global__ __launch_bounds__(1024) void scan_kernel(const int* __restrict__ cnt,
                                                    int* __restrict__ offs, int n) {
  __shared__ int partial[1024];
  int t = threadIdx.x;
  int per = (n + 1023) / 1024;
  int beg = t * per;
  int end = min(beg + per, n);
  int sum = 0;
  for (int i = beg; i < end; ++i) sum += cnt[i];
  partial[t] = sum;
  __syncthreads();
  for (int d = 1; d < 1024; d <<= 1) {
    int v = (t >= d) ? partial[t - d] : 0;
    __syncthreads();
    partial[t] += v;
    __syncthreads();
  }
  int excl = (t == 0) ? 0 : partial[t - 1];
  for (int i = beg; i < end; ++i) { offs[i] = excl; excl += cnt[i]; }
  if (t == 1023) offs[n] = partial[1023];
}

__global__ void init_self_kernel(const int* __restrict__ offs, int* __restrict__ srcs,
                                 int* __restrict__ fill, int n) {
  int i = blockIdx.x * blockDim.x + threadIdx.x;
  if (i < n) { srcs[offs[i]] = i; fill[i] = 1; }
}

__global__ void scatter_kernel(const void* __restrict__ ei, const int* __restrict__ flag, int E,
                               const int* __restrict__ offs, int* __restrict__ fill,
                               int* __restrict__ srcs) {
  int e = blockIdx.x * blockDim.x + threadIdx.x;
  if (e >= E) return;
  int is64 = *flag;
  int s = load_edge(ei, e, is64);
  int d = load_edge(ei, (long)E + e, is64);
  int pos = offs[d] + atomicAdd(&fill[d], 1);
  srcs[pos] = s;
}

// ---------------- packers: emit tile-panel-major layout [rt][kc][r128][8] ----------------
// (R5 win: +76% on GEMM. Element (row,k) lives at P[row>>7][k>>3][row&127][k&7],
// so each GEMM K-iter stages one CONTIGUOUS 8KB span per operand.)

// x f32 [M][K] -> packed bf16 [Mpad/128][Kpad/8][128][8]; rows>=M zero-filled.
__global__ __launch_bounds__(256) void pack_a_kernel(const float* __restrict__ in,
                                                     unsigned short* __restrict__ out, int M,
                                                     int K, int Kpad) {
  int rt = blockIdx.x;
  int r = threadIdx.x & 127;
  int kq = threadIdx.x >> 7;  // 0..1
  int row = rt * 128 + r;
  int nkc = Kpad >> 3;
  unsigned short* obase = out + (long)rt * Kpad * 128 + r * 8;
  const float* irow = in + (long)row * K;
  for (int kc = kq + (int)blockIdx.y * 2; kc < nkc; kc += (int)gridDim.y * 2) {
    int k = kc << 3;
    shortx8 o;
    if (row < M && k + 8 <= K && (K & 3) == 0) {
      float4 v0 = *(const float4*)(irow + k);
      float4 v1 = *(const float4*)(irow + k + 4);
      o[0] = (short)f2bf(v0.x); o[1] = (short)f2bf(v0.y);
      o[2] = (short)f2bf(v0.z); o[3] = (short)f2bf(v0.w);
      o[4] = (short)f2bf(v1.x); o[5] = (short)f2bf(v1.y);
      o[6] = (short)f2bf(v1.z); o[7] = (short)f2bf(v1.w);
    } else {
#pragma unroll
      for (int i = 0; i < 8; ++i) {
        int kk = k + i;
        float v = (row < M && kk < K) ? irow[kk] : 0.f;
        o[i] = (short)f2bf(v);
      }
    }
    *(shortx8*)(obase + (long)kc * 1024) = o;
  }
}

// W f32 [K][N] -> packed bf16 [N/128][Kpad/8][128][8] (transpose + pack).
__global__ __launch_bounds__(256) void transpose_pack_kernel(const float* __restrict__ in,
                                                             unsigned short* __restrict__ out,
                                                             int K, int N, int Kpad) {
  __shared__ float tile[32][33];
  int kb = blockIdx.x * 32;
  int nb = blockIdx.y * 32;
  int tx = threadIdx.x & 31;
  int ty = threadIdx.x >> 5;
#pragma unroll
  for (int i = 0; i < 32; i += 8) {
    int k = kb + ty + i;
    tile[ty + i][tx] = (k < K) ? in[(long)k * N + nb + tx] : 0.f;
  }
  __syncthreads();
  if (threadIdx.x < 128) {
    int nl = threadIdx.x & 31;
    int nn = nb + nl;
    int kc4 = threadIdx.x >> 5;  // 0..3
    int k0 = kc4 * 8;
    shortx8 o;
#pragma unroll
    for (int j = 0; j < 8; ++j) o[j] = (short)f2bf(tile[k0 + j][nl]);
    int kc = (kb >> 3) + kc4;
    *(shortx8*)(out + (long)(nn >> 7) * Kpad * 128 + (long)kc * 1024 + (nn & 127) * 8) = o;
  }
}

// ---------------- bf16 MFMA GEMM — packed operands, 2-DEEP prefetch, 3 LDS buffers ----------------
// (R10-proven: 187us/dispatch, MfmaUtil 30.3. Byte-identical here.)
// C[M,N] = A[M,K] * Bt[N,K]^T, both operands packed [*/128][K/8][128][8].
// Per K-step: issue tile k+2's 4 DMA loads -> s_waitcnt vmcnt(8) (tiles
// k+1,k+2 = 8 loads STAY IN FLIGHT across the bare s_barrier; never vmcnt(0)
// mid-loop) -> barrier -> frags + 16 MFMA -> bare barrier.
// Hazard audit (R3/R10): stage target buf (k+2)%3 == (k-1)%3; all reads of that
// buffer retired before iter k-1's trailing barrier (MFMA data-dep drained
// lgkm), and the DMA issues only after this wave passed that barrier -> no WAR
// race. RAW: vmcnt(8) retires tile k's 4 oldest loads; barrier publishes all
// waves' DMA writes before fragment reads.
// Tail ladder: vmcnt(8) -> vmcnt(4) (iter nk-2) -> vmcnt(0) (iter nk-1).
//   0x0F78=vmcnt(8)  0x0F74=vmcnt(4)  0x0F70=vmcnt(0).
// LDS 48KB -> 3 blocks/CU. Requires K%32==0, N%128==0, A packed to grid rows.
template <typename OT>
__global__ __launch_bounds__(256) void mfma_gemm_kernel(const unsigned short* __restrict__ A,
                                                        const unsigned short* __restrict__ Bt,
                                                        OT* __restrict__ C, int M, int N, int K) {
  __shared__ unsigned short As[3][4096];
  __shared__ unsigned short Bs[3][4096];

  int tid = threadIdx.x;
  int lane = tid & 63;
  int w = tid >> 6;
  int wm = w & 1, wn = w >> 1;
  int bn = blockIdx.x * 128;  // N-tile fastest
  int bm = blockIdx.y * 128;
  int quad = lane >> 4, l16 = lane & 15;

  const unsigned short* pA = A + (long)(bm >> 7) * K * 128 + tid * 8;
  const unsigned short* pB = Bt + (long)(bn >> 7) * K * 128 + tid * 8;
  unsigned short* la = &As[0][0] + w * 512;
  unsigned short* lb = &Bs[0][0] + w * 512;

  floatx4 acc[4][4];
#pragma unroll
  for (int i = 0; i < 4; ++i)
#pragma unroll
    for (int j = 0; j < 4; ++j) acc[i][j] = (floatx4){0.f, 0.f, 0.f, 0.f};

  int nk = K >> 5;
  // prologue: tile 0 -> buf0, tile 1 -> buf1
  gload_lds16(pA, la);
  gload_lds16(pA + 2048, la + 2048);
  gload_lds16(pB, lb);
  gload_lds16(pB + 2048, lb + 2048);
  if (nk > 1) {
    gload_lds16(pA + 4096, la + 4096);
    gload_lds16(pA + 4096 + 2048, la + 4096 + 2048);
    gload_lds16(pB + 4096, lb + 4096);
    gload_lds16(pB + 4096 + 2048, lb + 4096 + 2048);
  }

  int cur = 0, st = 2;
  for (int k = 0; k < nk; ++k) {
    if (k + 2 < nk) {
      const unsigned short* qA = pA + (long)(k + 2) * 4096;
      const unsigned short* qB = pB + (long)(k + 2) * 4096;
      unsigned short* da = la + st * 4096;
      unsigned short* db = lb + st * 4096;
      gload_lds16(qA, da);
      gload_lds16(qA + 2048, da + 2048);
      gload_lds16(qB, db);
      gload_lds16(qB + 2048, db + 2048);
      __builtin_amdgcn_s_waitcnt(0x0F78);  // vmcnt(8): tile k done, k+1/k+2 in flight
    } else if (k + 1 < nk) {
      __builtin_amdgcn_s_waitcnt(0x0F74);  // vmcnt(4): tile k done, k+1 in flight
    } else {
      __builtin_amdgcn_s_waitcnt(0x0F70);  // vmcnt(0): drain final tile
    }
    __builtin_amdgcn_s_barrier();  // bare barrier: in-flight DMA untouched

    shortx8 a[4], b[4];
#pragma unroll
    for (int i = 0; i < 4; ++i) {
      a[i] = *(const shortx8*)(&As[cur][(quad * 128 + wm * 64 + i * 16 + l16) * 8]);
      b[i] = *(const shortx8*)(&Bs[cur][(quad * 128 + wn * 64 + i * 16 + l16) * 8]);
    }
#pragma unroll
    for (int i = 0; i < 4; ++i)
#pragma unroll
      for (int j = 0; j < 4; ++j)
        acc[i][j] = __builtin_amdgcn_mfma_f32_16x16x32_bf16(a[i], b[j], acc[i][j], 0, 0, 0);

    // WAR guard: all reads of the buffer the next stage overwrites retired here.
    __builtin_amdgcn_s_barrier();
    cur = (cur == 2) ? 0 : cur + 1;
    st = (st == 2) ? 0 : st + 1;
  }

  // epilogue: C/D layout col=lane&15, row=quad*4+reg
  int orow0 = bm + wm * 64 + quad * 4;
  int ocol0 = bn + wn * 64 + l16;
#pragma unroll
  for (int i = 0; i < 4; ++i)
#pragma unroll
    for (int j = 0; j < 4; ++j)
#pragma unroll
      for (int r2 = 0; r2 < 4; ++r2) {
        int rr = orow0 + i * 16 + r2;
        if (rr < M) store_out(&C[(long)rr * N + ocol0 + j * 16], acc[i][j][r2]);
      }
}

// ---------------- attention coefficients from bf16 h ----------------
__global__ __launch_bounds__(256) void att_coef_kernel(const unsigned short* __restrict__ h,
                                                       const float* __restrict__ att_s,
                                                       const float* __restrict__ att_d,
                                                       float* __restrict__ a_s,
                                                       float* __restrict__ a_d, int n, int H,
                                                       int C) {
  int wave = (int)((blockIdx.x * blockDim.x + threadIdx.x) >> 6);
  int lane = threadIdx.x & 63;
  if (wave >= n) return;
  const unsigned short* row = h + (long)wave * H * C;
  for (int hh = 0; hh < H; ++hh) {
    float s = 0.f, d = 0.f;
    for (int c = lane; c < C; c += 64) {
      float v = bf2f(row[hh * C + c]);
      s += v * att_s[hh * C + c];
      d += v * att_d[hh * C + c];
    }
#pragma unroll
    for (int o = 32; o > 0; o >>= 1) {
      s += __shfl_down(s, o, 64);
      d += __shfl_down(d, o, 64);
    }
    if (lane == 0) {
      a_s[(long)wave * H + hh] = s;
      a_d[(long)wave * H + hh] = d;
    }
  }
}

// ---------------- per-(dst,head) segment softmax over CSR ----------------
__global__ void edge_softmax_kernel(const float* __restrict__ a_src,
                                    const float* __restrict__ a_dst,
                                    const int* __restrict__ offs, const int* __restrict__ srcs,
                                    float* __restrict__ alpha, int n, int H) {
  int idx = blockIdx.x * blockDim.x + threadIdx.x;
  if (idx >= n * H) return;
  int dstn = idx / H;
  int hh = idx - dstn * H;
  int beg = offs[dstn], end = offs[dstn + 1];
  float ad = a_dst[idx];
  float m = -1e30f;
  for (int j = beg; j < end; ++j) {
    float e = a_src[srcs[j] * H + hh] + ad;
    e = e > 0.f ? e : NEG_SLOPE * e;
    m = fmaxf(m, e);
  }
  float ssum = 0.f;
  for (int j = beg; j < end; ++j) {
    float e = a_src[srcs[j] * H + hh] + ad;
    e = e > 0.f ? e : NEG_SLOPE * e;
    float ex = __expf(e - m);
    alpha[(long)j * H + hh] = ex;
    ssum += ex;
  }
  float inv = 1.f / ssum;
  for (int j = beg; j < end; ++j) alpha[(long)j * H + hh] *= inv;
}

// ---------------- layer-1 aggregation: 8-dst blocks, coalesced packed write ----------------
// R10 post-mortem: the R5 form (1 dst/block, 320 threads over fids) emitted 320
// ISOLATED 16B stores at 2KB stride per block into the packed layout -> every
// 64B line filled for a 16B write (~4x amplification on 52MB ~ +109us, the
// R0-vs-R5 non-GEMM delta). Packed layout fact: for fixed kc, consecutive ROWS
// are consecutive 16B cells. So: one block = 8 CONSECUTIVE dsts (8 | 128, never
// crosses a row-tile); thread t -> sub=t&7 (dst), fid=(t>>3)+32*it.
//   Writes: lanes 0..7 share fid across 8 consecutive dsts -> one contiguous
//   128B segment (2 full lines, zero amplification).
//   Reads: for fixed sub, the 8 fgrp-lanes read 8 consecutive fids of the SAME
//   src row (lockstep j: same dst -> same edge list) -> 128B contiguous.
// dst in [Nn, Mpad): beg==end -> writes relu(bias) garbage rows; those A-rows
// only affect C-rows >= Nn, which the GEMM epilogue guards (rr < M).
__global__ __launch_bounds__(256) void aggregate1_kernel(const unsigned short* __restrict__ h,
                                                         const float* __restrict__ alpha,
                                                         const int* __restrict__ offs,
                                                         const int* __restrict__ srcs,
                                                         const float* __restrict__ bias,
                                                         unsigned short* __restrict__ out, int H,
                                                         int C, int HC, int Nn) {
  int sub = threadIdx.x & 7;
  int fgrp = threadIdx.x >> 3;  // 0..31
  int dst = blockIdx.x * 8 + sub;
  int nf8 = HC >> 3;
  int beg = 0, end = 0;
  if (dst < Nn) { beg = offs[dst]; end = offs[dst + 1]; }
  unsigned short* obase = out + (long)(dst >> 7) * HC * 128 + (dst & 127) * 8;
  for (int fid = fgrp; fid < nf8; fid += 32) {
    int hh = (fid << 3) / C;
    const unsigned short* hsrc = h + (fid << 3);
    float acc[8];
#pragma unroll
    for (int i = 0; i < 8; ++i) acc[i] = 0.f;
    for (int j = beg; j < end; ++j) {
      int s = srcs[j];
      float al = alpha[(long)j * H + hh];
      shortx8 r = *(const shortx8*)(hsrc + (long)s * HC);
#pragma unroll
      for (int i = 0; i < 8; ++i) acc[i] = fmaf(al, bf2f((unsigned short)r[i]), acc[i]);
    }
    shortx8 o;
#pragma unroll
    for (int i = 0; i < 8; ++i) {
      float bb = bias[(fid << 3) + i];
      o[i] = (short)f2bf(fmaxf(acc[i] + bb, 0.f));
    }
    *(shortx8*)(obase + (long)fid * 1024) = o;
  }
}

// ---------------- layer-2 aggregation with head-mean: bf16 h -> fp32 out (R5-proven) ----------------
__global__ __launch_bounds__(128) void aggregate2_kernel(const unsigned short* __restrict__ h,
                                                         const float* __restrict__ alpha,
                                                         const int* __restrict__ offs,
                                                         const int* __restrict__ srcs,
                                                         const float* __restrict__ bias,
                                                         float* __restrict__ out, int H, int C) {
  int dstn = blockIdx.x;
  int c = threadIdx.x;
  if (c >= C) return;
  int beg = offs[dstn], end = offs[dstn + 1];
  int HC = H * C;
  float acc = 0.f;
  for (int j = beg; j < end; ++j) {
    int s = srcs[j];
    const unsigned short* row = h + (long)s * HC;
    const float* al = alpha + (long)j * H;
#pragma unroll 5
    for (int hh = 0; hh < H; ++hh) acc = fmaf(al[hh], bf2f(row[hh * C + c]), acc);
  }
  float v = acc * (1.f / (float)H) + bias[c];
  out[(long)dstn * C + c] = v > 0.f ? v : 0.f;
}

// ---------------- host ----------------
static inline size_t align256(size_t x) { return (x + 255) & ~(size_t)255; }

extern "C" void kernel_launch(void* const* d_in, const int* in_sizes, int n_in, void* d_out,
                              int out_size, void* d_ws, size_t ws_size, hipStream_t stream) {
  const float* x        = (const float*)d_in[0];
  const void*  ei       = d_in[1];
  const float* W1       = (const float*)d_in[2];
  const float* att_src1 = (const float*)d_in[3];
  const float* att_dst1 = (const float*)d_in[4];
  const float* b1       = (const float*)d_in[5];
  const float* W2       = (const float*)d_in[6];
  const float* att_src2 = (const float*)d_in[7];
  const float* att_dst2 = (const float*)d_in[8];
  const float* b2       = (const float*)d_in[9];
  float* out = (float*)d_out;

  const int C2  = in_sizes[9];       // 128
  const int H   = in_sizes[7] / C2;  // 20
  const int HC1 = in_sizes[5];       // 2560
  const int C1  = HC1 / H;           // 128
  const int G   = in_sizes[2] / HC1; // 2000
  const int Nn  = in_sizes[0] / G;   // 10000
  const int E   = in_sizes[1] / 2;   // 100000
  const int HC2 = H * C2;            // 2560
  const int Et  = E + Nn;
  const int Mpad = ((Nn + 127) / 128) * 128;
  const int K1pad = ((G + 31) / 32) * 32;  // 2048

  // workspace layout — R5-exact
  char* p = (char*)d_ws;
  size_t off = 0;
  unsigned short* hb  = (unsigned short*)(p + off); off = align256(off + (size_t)Mpad * (HC1 > HC2 ? HC1 : HC2) * 2);
  unsigned short* xb  = (unsigned short*)(p + off); off = align256(off + (size_t)Mpad * K1pad * 2);
  unsigned short* xb2 = (unsigned short*)(p + off); off = align256(off + (size_t)Mpad * HC1 * 2);
  unsigned short* W1t = (unsigned short*)(p + off); off = align256(off + (size_t)HC1 * K1pad * 2);
  unsigned short* W2t = (unsigned short*)(p + off); off = align256(off + (size_t)HC2 * HC1 * 2);
  float* a_s   = (float*)(p + off); off = align256(off + (size_t)Nn * H * 4);
  float* a_d   = (float*)(p + off); off = align256(off + (size_t)Nn * H * 4);
  float* alpha = (float*)(p + off); off = align256(off + (size_t)Et * H * 4);
  int* cnt     = (int*)(p + off); off = align256(off + (size_t)Nn * 4);
  int* offs    = (int*)(p + off); off = align256(off + (size_t)(Nn + 1) * 4);
  int* fill    = (int*)(p + off); off = align256(off + (size_t)Nn * 4);
  int* srcs    = (int*)(p + off); off = align256(off + (size_t)Et * 4);
  int* flag64  = (int*)(p + off); off = align256(off + 16);
  (void)ws_size; (void)n_in; (void)out_size;

  const int TB = 256;
  // CSR build
  detect64_kernel<<<1, 1, 0, stream>>>((const unsigned int*)ei, flag64);
  init_cnt_kernel<<<(Nn + TB - 1) / TB, TB, 0, stream>>>(cnt, Nn);
  count_kernel<<<(E + TB - 1) / TB, TB, 0, stream>>>(ei, flag64, E, cnt);
  scan_kernel<<<1, 1024, 0, stream>>>(cnt, offs, Nn);
  init_self_kernel<<<(Nn + TB - 1) / TB, TB, 0, stream>>>(offs, srcs, fill, Nn);
  scatter_kernel<<<(E + TB - 1) / TB, TB, 0, stream>>>(ei, flag64, E, offs, fill, srcs);

  // packed-layout operand prep
  {
    dim3 ga(Mpad / 128, 8);
    pack_a_kernel<<<ga, 256, 0, stream>>>(x, xb, Nn, G, K1pad);
    dim3 g1(K1pad / 32, HC1 / 32);
    transpose_pack_kernel<<<g1, 256, 0, stream>>>(W1, W1t, G, HC1, K1pad);
    dim3 g2(HC1 / 32, HC2 / 32);
    transpose_pack_kernel<<<g2, 256, 0, stream>>>(W2, W2t, HC1, HC2, HC1);
  }

  // layer 1
  {
    dim3 grid(HC1 / 128, Mpad / 128);  // N-tile fastest
    mfma_gemm_kernel<unsigned short><<<grid, 256, 0, stream>>>(xb, W1t, hb, Nn, HC1, K1pad);
  }
  att_coef_kernel<<<(Nn + 3) / 4, 256, 0, stream>>>(hb, att_src1, att_dst1, a_s, a_d, Nn, H, C1);
  edge_softmax_kernel<<<(Nn * H + TB - 1) / TB, TB, 0, stream>>>(a_s, a_d, offs, srcs, alpha, Nn, H);
  aggregate1_kernel<<<Mpad / 8, 256, 0, stream>>>(hb, alpha, offs, srcs, b1, xb2, H, C1, HC1, Nn);

  // layer 2
  {
    dim3 grid(HC2 / 128, Mpad / 128);
    mfma_gemm_kernel<unsigned short><<<grid, 256, 0, stream>>>(xb2, W2t, hb, Nn, HC2, HC1);
  }
  att_coef_kernel<<<(Nn + 3) / 4, 256, 0, stream>>>(hb, att_src2, att_dst2, a_s, a_d, Nn, H, C2);
  edge_softmax_kernel<<<(Nn * H + TB - 1) / TB, TB, 0, stream>>>(a_s, a_d, offs, srcs, alpha, Nn, H);
  aggregate2_kernel<<<Nn, 128, 0, stream>>>(hb, alpha, offs, srcs, b2, out, H, C2);
}

// Round 12
// 869.483 us; speedup vs baseline: 1.0424x; 1.0424x over previous
//
#include <hip/hip_runtime.h>

#define NEG_SLOPE 0.2f

typedef __attribute__((ext_vector_type(4))) float floatx4;
typedef __attribute__((ext_vector_type(8))) short shortx8;

__device__ __forceinline__ unsigned short f2bf(float f) {
  union { float f; unsigned int u; } v;
  v.f = f;
  unsigned int r = (v.u + 0x7FFFu + ((v.u >> 16) & 1u)) >> 16;
  return (unsigned short)r;
}
__device__ __forceinline__ float bf2f(unsigned short u) {
  union { unsigned int u; float f; } v;
  v.u = (unsigned int)u << 16;
  return v.f;
}
__device__ __forceinline__ void store_out(float* p, float v) { *p = v; }
__device__ __forceinline__ void store_out(unsigned short* p, float v) { *p = f2bf(v); }

// async global->LDS, 16B per lane, LDS dest = wave-uniform base + lane*16
__device__ __forceinline__ void gload_lds16(const unsigned short* g, unsigned short* l) {
  __builtin_amdgcn_global_load_lds(
      (const __attribute__((address_space(1))) void*)(g),
      (__attribute__((address_space(3))) void*)(l), 16, 0, 0);
}

// ---------------- edge index width detection (int32 vs int64) ----------------
__device__ __forceinline__ int load_edge(const void* ei, long idx, int is64) {
  if (is64) return (int)((const long long*)ei)[idx];
  return ((const int*)ei)[idx];
}

__global__ void detect64_kernel(const unsigned int* __restrict__ p, int* __restrict__ flag) {
  int is64 = 1;
  for (int i = 0; i < 32; ++i)
    if (p[2 * i + 1] != 0u) is64 = 0;
  *flag = is64;
}

// ---------------- CSR build ----------------
__global__ void init_cnt_kernel(int* __restrict__ cnt, int n) {
  int i = blockIdx.x * blockDim.x + threadIdx.x;
  if (i < n) cnt[i] = 1;  // self-loop
}

__global__ void count_kernel(const void* __restrict__ ei, const int* __restrict__ flag, int E,
                             int* __restrict__ cnt) {
  int e = blockIdx.x * blockDim.x + threadIdx.x;
  if (e >= E) return;
  int is64 = *flag;
  int d = load_edge(ei, (long)E + e, is64);
  atomicAdd(&cnt[d], 1);
}

__global__ __launch_bounds__(1024) void scan_kernel(const int* __restrict__ cnt,
                                                    int* __restrict__ offs, int n) {
  __shared__ int partial[1024];
  int t = threadIdx.x;
  int per = (n + 1023) / 1024;
  int beg = t * per;
  int end = min(beg + per, n);
  int sum = 0;
  for (int i = beg; i < end; ++i) sum += cnt[i];
  partial[t] = sum;
  __syncthreads();
  for (int d = 1; d < 1024; d <<= 1) {
    int v = (t >= d) ? partial[t - d] : 0;
    __syncthreads();
    partial[t] += v;
    __syncthreads();
  }
  int excl = (t == 0) ? 0 : partial[t - 1];
  for (int i = beg; i < end; ++i) { offs[i] = excl; excl += cnt[i]; }
  if (t == 1023) offs[n] = partial[1023];
}

__global__ void init_self_kernel(const int* __restrict__ offs, int* __restrict__ srcs,
                                 int* __restrict__ fill, int n) {
  int i = blockIdx.x * blockDim.x + threadIdx.x;
  if (i < n) { srcs[offs[i]] = i; fill[i] = 1; }
}

__global__ void scatter_kernel(const void* __restrict__ ei, const int* __restrict__ flag, int E,
                               const int* __restrict__ offs, int* __restrict__ fill,
                               int* __restrict__ srcs) {
  int e = blockIdx.x * blockDim.x + threadIdx.x;
  if (e >= E) return;
  int is64 = *flag;
  int s = load_edge(ei, e, is64);
  int d = load_edge(ei, (long)E + e, is64);
  int pos = offs[d] + atomicAdd(&fill[d], 1);
  srcs[pos] = s;
}

// ---------------- packers: emit tile-panel-major layout [rt][kc][r128][8] ----------------
// (R5 win: +76% on GEMM. Element (row,k) lives at P[row>>7][k>>3][row&127][k&7],
// so each GEMM K-iter stages one CONTIGUOUS 8KB span per operand.)

// x f32 [M][K] -> packed bf16 [Mpad/128][Kpad/8][128][8]; rows>=M zero-filled.
__global__ __launch_bounds__(256) void pack_a_kernel(const float* __restrict__ in,
                                                     unsigned short* __restrict__ out, int M,
                                                     int K, int Kpad) {
  int rt = blockIdx.x;
  int r = threadIdx.x & 127;
  int kq = threadIdx.x >> 7;  // 0..1
  int row = rt * 128 + r;
  int nkc = Kpad >> 3;
  unsigned short* obase = out + (long)rt * Kpad * 128 + r * 8;
  const float* irow = in + (long)row * K;
  for (int kc = kq + (int)blockIdx.y * 2; kc < nkc; kc += (int)gridDim.y * 2) {
    int k = kc << 3;
    shortx8 o;
    if (row < M && k + 8 <= K && (K & 3) == 0) {
      float4 v0 = *(const float4*)(irow + k);
      float4 v1 = *(const float4*)(irow + k + 4);
      o[0] = (short)f2bf(v0.x); o[1] = (short)f2bf(v0.y);
      o[2] = (short)f2bf(v0.z); o[3] = (short)f2bf(v0.w);
      o[4] = (short)f2bf(v1.x); o[5] = (short)f2bf(v1.y);
      o[6] = (short)f2bf(v1.z); o[7] = (short)f2bf(v1.w);
    } else {
#pragma unroll
      for (int i = 0; i < 8; ++i) {
        int kk = k + i;
        float v = (row < M && kk < K) ? irow[kk] : 0.f;
        o[i] = (short)f2bf(v);
      }
    }
    *(shortx8*)(obase + (long)kc * 1024) = o;
  }
}

// W f32 [K][N] -> packed bf16 [N/128][Kpad/8][128][8] (transpose + pack).
__global__ __launch_bounds__(256) void transpose_pack_kernel(const float* __restrict__ in,
                                                             unsigned short* __restrict__ out,
                                                             int K, int N, int Kpad) {
  __shared__ float tile[32][33];
  int kb = blockIdx.x * 32;
  int nb = blockIdx.y * 32;
  int tx = threadIdx.x & 31;
  int ty = threadIdx.x >> 5;
#pragma unroll
  for (int i = 0; i < 32; i += 8) {
    int k = kb + ty + i;
    tile[ty + i][tx] = (k < K) ? in[(long)k * N + nb + tx] : 0.f;
  }
  __syncthreads();
  if (threadIdx.x < 128) {
    int nl = threadIdx.x & 31;
    int nn = nb + nl;
    int kc4 = threadIdx.x >> 5;  // 0..3
    int k0 = kc4 * 8;
    shortx8 o;
#pragma unroll
    for (int j = 0; j < 8; ++j) o[j] = (short)f2bf(tile[k0 + j][nl]);
    int kc = (kb >> 3) + kc4;
    *(shortx8*)(out + (long)(nn >> 7) * Kpad * 128 + (long)kc * 1024 + (nn & 127) * 8) = o;
  }
}

// ---------------- bf16 MFMA GEMM — packed operands, 2-DEEP prefetch, 3 LDS buffers ----------------
// (R10-proven: ~187us/dispatch, MfmaUtil 30. Byte-identical here.)
// C[M,N] = A[M,K] * Bt[N,K]^T, both operands packed [*/128][K/8][128][8].
// Per K-step: issue tile k+2's 4 DMA loads -> s_waitcnt vmcnt(8) (tiles
// k+1,k+2 = 8 loads STAY IN FLIGHT across the bare s_barrier; never vmcnt(0)
// mid-loop) -> barrier -> frags + 16 MFMA -> bare barrier.
// Hazard audit (R3/R10): stage target buf (k+2)%3 == (k-1)%3; all reads of that
// buffer retired before iter k-1's trailing barrier (MFMA data-dep drained
// lgkm), and the DMA issues only after this wave passed that barrier -> no WAR
// race. RAW: vmcnt(8) retires tile k's 4 oldest loads; barrier publishes all
// waves' DMA writes before fragment reads.
// Tail ladder: vmcnt(8) -> vmcnt(4) (iter nk-2) -> vmcnt(0) (iter nk-1).
//   0x0F78=vmcnt(8)  0x0F74=vmcnt(4)  0x0F70=vmcnt(0).
// LDS 48KB -> 3 blocks/CU. Requires K%32==0, N%128==0, A packed to grid rows.
template <typename OT>
__global__ __launch_bounds__(256) void mfma_gemm_kernel(const unsigned short* __restrict__ A,
                                                        const unsigned short* __restrict__ Bt,
                                                        OT* __restrict__ C, int M, int N, int K) {
  __shared__ unsigned short As[3][4096];
  __shared__ unsigned short Bs[3][4096];

  int tid = threadIdx.x;
  int lane = tid & 63;
  int w = tid >> 6;
  int wm = w & 1, wn = w >> 1;
  int bn = blockIdx.x * 128;  // N-tile fastest
  int bm = blockIdx.y * 128;
  int quad = lane >> 4, l16 = lane & 15;

  const unsigned short* pA = A + (long)(bm >> 7) * K * 128 + tid * 8;
  const unsigned short* pB = Bt + (long)(bn >> 7) * K * 128 + tid * 8;
  unsigned short* la = &As[0][0] + w * 512;
  unsigned short* lb = &Bs[0][0] + w * 512;

  floatx4 acc[4][4];
#pragma unroll
  for (int i = 0; i < 4; ++i)
#pragma unroll
    for (int j = 0; j < 4; ++j) acc[i][j] = (floatx4){0.f, 0.f, 0.f, 0.f};

  int nk = K >> 5;
  // prologue: tile 0 -> buf0, tile 1 -> buf1
  gload_lds16(pA, la);
  gload_lds16(pA + 2048, la + 2048);
  gload_lds16(pB, lb);
  gload_lds16(pB + 2048, lb + 2048);
  if (nk > 1) {
    gload_lds16(pA + 4096, la + 4096);
    gload_lds16(pA + 4096 + 2048, la + 4096 + 2048);
    gload_lds16(pB + 4096, lb + 4096);
    gload_lds16(pB + 4096 + 2048, lb + 4096 + 2048);
  }

  int cur = 0, st = 2;
  for (int k = 0; k < nk; ++k) {
    if (k + 2 < nk) {
      const unsigned short* qA = pA + (long)(k + 2) * 4096;
      const unsigned short* qB = pB + (long)(k + 2) * 4096;
      unsigned short* da = la + st * 4096;
      unsigned short* db = lb + st * 4096;
      gload_lds16(qA, da);
      gload_lds16(qA + 2048, da + 2048);
      gload_lds16(qB, db);
      gload_lds16(qB + 2048, db + 2048);
      __builtin_amdgcn_s_waitcnt(0x0F78);  // vmcnt(8): tile k done, k+1/k+2 in flight
    } else if (k + 1 < nk) {
      __builtin_amdgcn_s_waitcnt(0x0F74);  // vmcnt(4): tile k done, k+1 in flight
    } else {
      __builtin_amdgcn_s_waitcnt(0x0F70);  // vmcnt(0): drain final tile
    }
    __builtin_amdgcn_s_barrier();  // bare barrier: in-flight DMA untouched

    shortx8 a[4], b[4];
#pragma unroll
    for (int i = 0; i < 4; ++i) {
      a[i] = *(const shortx8*)(&As[cur][(quad * 128 + wm * 64 + i * 16 + l16) * 8]);
      b[i] = *(const shortx8*)(&Bs[cur][(quad * 128 + wn * 64 + i * 16 + l16) * 8]);
    }
#pragma unroll
    for (int i = 0; i < 4; ++i)
#pragma unroll
      for (int j = 0; j < 4; ++j)
        acc[i][j] = __builtin_amdgcn_mfma_f32_16x16x32_bf16(a[i], b[j], acc[i][j], 0, 0, 0);

    // WAR guard: all reads of the buffer the next stage overwrites retired here.
    __builtin_amdgcn_s_barrier();
    cur = (cur == 2) ? 0 : cur + 1;
    st = (st == 2) ? 0 : st + 1;
  }

  // epilogue: C/D layout col=lane&15, row=quad*4+reg
  int orow0 = bm + wm * 64 + quad * 4;
  int ocol0 = bn + wn * 64 + l16;
#pragma unroll
  for (int i = 0; i < 4; ++i)
#pragma unroll
    for (int j = 0; j < 4; ++j)
#pragma unroll
      for (int r2 = 0; r2 < 4; ++r2) {
        int rr = orow0 + i * 16 + r2;
        if (rr < M) store_out(&C[(long)rr * N + ocol0 + j * 16], acc[i][j][r2]);
      }
}

// ---------------- attention coefficients from bf16 h ----------------
__global__ __launch_bounds__(256) void att_coef_kernel(const unsigned short* __restrict__ h,
                                                       const float* __restrict__ att_s,
                                                       const float* __restrict__ att_d,
                                                       float* __restrict__ a_s,
                                                       float* __restrict__ a_d, int n, int H,
                                                       int C) {
  int wave = (int)((blockIdx.x * blockDim.x + threadIdx.x) >> 6);
  int lane = threadIdx.x & 63;
  if (wave >= n) return;
  const unsigned short* row = h + (long)wave * H * C;
  for (int hh = 0; hh < H; ++hh) {
    float s = 0.f, d = 0.f;
    for (int c = lane; c < C; c += 64) {
      float v = bf2f(row[hh * C + c]);
      s += v * att_s[hh * C + c];
      d += v * att_d[hh * C + c];
    }
#pragma unroll
    for (int o = 32; o > 0; o >>= 1) {
      s += __shfl_down(s, o, 64);
      d += __shfl_down(d, o, 64);
    }
    if (lane == 0) {
      a_s[(long)wave * H + hh] = s;
      a_d[(long)wave * H + hh] = d;
    }
  }
}

// ---------------- per-(dst,head) segment softmax over CSR ----------------
__global__ void edge_softmax_kernel(const float* __restrict__ a_src,
                                    const float* __restrict__ a_dst,
                                    const int* __restrict__ offs, const int* __restrict__ srcs,
                                    float* __restrict__ alpha, int n, int H) {
  int idx = blockIdx.x * blockDim.x + threadIdx.x;
  if (idx >= n * H) return;
  int dstn = idx / H;
  int hh = idx - dstn * H;
  int beg = offs[dstn], end = offs[dstn + 1];
  float ad = a_dst[idx];
  float m = -1e30f;
  for (int j = beg; j < end; ++j) {
    float e = a_src[srcs[j] * H + hh] + ad;
    e = e > 0.f ? e : NEG_SLOPE * e;
    m = fmaxf(m, e);
  }
  float ssum = 0.f;
  for (int j = beg; j < end; ++j) {
    float e = a_src[srcs[j] * H + hh] + ad;
    e = e > 0.f ? e : NEG_SLOPE * e;
    float ex = __expf(e - m);
    alpha[(long)j * H + hh] = ex;
    ssum += ex;
  }
  float inv = 1.f / ssum;
  for (int j = beg; j < end; ++j) alpha[(long)j * H + hh] *= inv;
}

// ---------------- layer-1 aggregation: bf16 h -> packed bf16 xb2 (R5/R10-proven) ----------------
// One dst per block: the WHOLE block walks one edge list in lockstep; lanes
// read consecutive fids of the same src row -> fully coalesced reads (the 563MB
// side). Packed write is 16B-strided (write amplification) but writes are only
// ~52MB — R11 proved trading read coalescing for write coalescing loses 64us.
__global__ __launch_bounds__(320) void aggregate1_kernel(const unsigned short* __restrict__ h,
                                                         const float* __restrict__ alpha,
                                                         const int* __restrict__ offs,
                                                         const int* __restrict__ srcs,
                                                         const float* __restrict__ bias,
                                                         unsigned short* __restrict__ out, int H,
                                                         int C, int HC) {
  int dstn = blockIdx.x;
  int t = threadIdx.x;
  int beg = offs[dstn], end = offs[dstn + 1];
  int nf8 = HC >> 3;
  for (int fid = t; fid < nf8; fid += blockDim.x) {
    int hh = (fid << 3) / C;
    float acc[8];
#pragma unroll
    for (int i = 0; i < 8; ++i) acc[i] = 0.f;
    for (int j = beg; j < end; ++j) {
      int s = srcs[j];
      float al = alpha[(long)j * H + hh];
      shortx8 r = ((const shortx8*)(h + (long)s * HC))[fid];
#pragma unroll
      for (int i = 0; i < 8; ++i) acc[i] = fmaf(al, bf2f((unsigned short)r[i]), acc[i]);
    }
    shortx8 o;
#pragma unroll
    for (int i = 0; i < 8; ++i) {
      float bb = bias[(fid << 3) + i];
      o[i] = (short)f2bf(fmaxf(acc[i] + bb, 0.f));
    }
    // packed layout: (row=dstn, kc=fid) -> [dstn>>7][fid][dstn&127][8]
    *(shortx8*)(out + (long)(dstn >> 7) * HC * 128 + (long)fid * 1024 + (dstn & 127) * 8) = o;
  }
}

// ---------------- layer-2 aggregation with head-mean: vectorized, NO atomics ----------------
// Old form: 128 threads, 20 scalar 2B loads per thread per edge (Common-mistake
// #2). R9's rewrite failed via LDS-atomic serialization; this one has none.
// Thread t -> c8 = t & (nc8-1) column-chunk, hgrp = t >> log2(nc8) head-slice.
// Per edge, wave lanes tile the src row CONTIGUOUSLY (hh*C*2 + c8*16 bytes):
// 1KB coalesced vector reads, 10x fewer load instructions. Each thread
// accumulates its <=2 heads in static regs acc[2][8]; heads reduced ONCE at the
// end through smem[nHgrp][C] (plain stores + strided sum, 2-way-free banks).
// Requires C%8==0, nc8=C/8 power-of-two<=256, H <= 2*(256/nc8).
__global__ __launch_bounds__(256) void aggregate2_kernel(const unsigned short* __restrict__ h,
                                                         const float* __restrict__ alpha,
                                                         const int* __restrict__ offs,
                                                         const int* __restrict__ srcs,
                                                         const float* __restrict__ bias,
                                                         float* __restrict__ out, int H, int C) {
  __shared__ float smem[16 * 256];  // nHgrp x C, C<=256
  int dstn = blockIdx.x;
  int t = threadIdx.x;
  int HC = H * C;
  int nc8 = C >> 3;                 // 16 for C=128
  int c8 = t & (nc8 - 1);
  int hgrp = t >> __builtin_ctz(nc8);  // 0..nHgrp-1
  int nHgrp = 256 >> __builtin_ctz(nc8);
  int beg = offs[dstn], end = offs[dstn + 1];

  float acc[2][8];
#pragma unroll
  for (int hi = 0; hi < 2; ++hi)
#pragma unroll
    for (int i = 0; i < 8; ++i) acc[hi][i] = 0.f;

  for (int j = beg; j < end; ++j) {
    int s = srcs[j];
    const unsigned short* row = h + (long)s * HC;
    const float* al = alpha + (long)j * H;
#pragma unroll
    for (int hi = 0; hi < 2; ++hi) {
      int hh = hgrp + hi * nHgrp;
      if (hh < H) {
        float a = al[hh];
        shortx8 r = *(const shortx8*)(row + hh * C + c8 * 8);
#pragma unroll
        for (int i = 0; i < 8; ++i) acc[hi][i] = fmaf(a, bf2f((unsigned short)r[i]), acc[hi][i]);
      }
    }
  }
  // fold this thread's two head-slices, park in smem[hgrp][c]
#pragma unroll
  for (int i = 0; i < 8; ++i) smem[hgrp * C + c8 * 8 + i] = acc[0][i] + acc[1][i];
  __syncthreads();
  float invH = 1.f / (float)H;
  for (int c = t; c < C; c += 256) {
    float s = 0.f;
    for (int g = 0; g < nHgrp; ++g) s += smem[g * C + c];
    float v = s * invH + bias[c];
    out[(long)dstn * C + c] = v > 0.f ? v : 0.f;
  }
}

// ---------------- host ----------------
static inline size_t align256(size_t x) { return (x + 255) & ~(size_t)255; }

extern "C" void kernel_launch(void* const* d_in, const int* in_sizes, int n_in, void* d_out,
                              int out_size, void* d_ws, size_t ws_size, hipStream_t stream) {
  const float* x        = (const float*)d_in[0];
  const void*  ei       = d_in[1];
  const float* W1       = (const float*)d_in[2];
  const float* att_src1 = (const float*)d_in[3];
  const float* att_dst1 = (const float*)d_in[4];
  const float* b1       = (const float*)d_in[5];
  const float* W2       = (const float*)d_in[6];
  const float* att_src2 = (const float*)d_in[7];
  const float* att_dst2 = (const float*)d_in[8];
  const float* b2       = (const float*)d_in[9];
  float* out = (float*)d_out;

  const int C2  = in_sizes[9];       // 128
  const int H   = in_sizes[7] / C2;  // 20
  const int HC1 = in_sizes[5];       // 2560
  const int C1  = HC1 / H;           // 128
  const int G   = in_sizes[2] / HC1; // 2000
  const int Nn  = in_sizes[0] / G;   // 10000
  const int E   = in_sizes[1] / 2;   // 100000
  const int HC2 = H * C2;            // 2560
  const int Et  = E + Nn;
  const int Mpad = ((Nn + 127) / 128) * 128;
  const int K1pad = ((G + 31) / 32) * 32;  // 2048

  // workspace layout — R5-exact
  char* p = (char*)d_ws;
  size_t off = 0;
  unsigned short* hb  = (unsigned short*)(p + off); off = align256(off + (size_t)Mpad * (HC1 > HC2 ? HC1 : HC2) * 2);
  unsigned short* xb  = (unsigned short*)(p + off); off = align256(off + (size_t)Mpad * K1pad * 2);
  unsigned short* xb2 = (unsigned short*)(p + off); off = align256(off + (size_t)Mpad * HC1 * 2);
  unsigned short* W1t = (unsigned short*)(p + off); off = align256(off + (size_t)HC1 * K1pad * 2);
  unsigned short* W2t = (unsigned short*)(p + off); off = align256(off + (size_t)HC2 * HC1 * 2);
  float* a_s   = (float*)(p + off); off = align256(off + (size_t)Nn * H * 4);
  float* a_d   = (float*)(p + off); off = align256(off + (size_t)Nn * H * 4);
  float* alpha = (float*)(p + off); off = align256(off + (size_t)Et * H * 4);
  int* cnt     = (int*)(p + off); off = align256(off + (size_t)Nn * 4);
  int* offs    = (int*)(p + off); off = align256(off + (size_t)(Nn + 1) * 4);
  int* fill    = (int*)(p + off); off = align256(off + (size_t)Nn * 4);
  int* srcs    = (int*)(p + off); off = align256(off + (size_t)Et * 4);
  int* flag64  = (int*)(p + off); off = align256(off + 16);
  (void)ws_size; (void)n_in; (void)out_size;

  const int TB = 256;
  // CSR build
  detect64_kernel<<<1, 1, 0, stream>>>((const unsigned int*)ei, flag64);
  init_cnt_kernel<<<(Nn + TB - 1) / TB, TB, 0, stream>>>(cnt, Nn);
  count_kernel<<<(E + TB - 1) / TB, TB, 0, stream>>>(ei, flag64, E, cnt);
  scan_kernel<<<1, 1024, 0, stream>>>(cnt, offs, Nn);
  init_self_kernel<<<(Nn + TB - 1) / TB, TB, 0, stream>>>(offs, srcs, fill, Nn);
  scatter_kernel<<<(E + TB - 1) / TB, TB, 0, stream>>>(ei, flag64, E, offs, fill, srcs);

  // packed-layout operand prep
  {
    dim3 ga(Mpad / 128, 8);
    pack_a_kernel<<<ga, 256, 0, stream>>>(x, xb, Nn, G, K1pad);
    dim3 g1(K1pad / 32, HC1 / 32);
    transpose_pack_kernel<<<g1, 256, 0, stream>>>(W1, W1t, G, HC1, K1pad);
    dim3 g2(HC1 / 32, HC2 / 32);
    transpose_pack_kernel<<<g2, 256, 0, stream>>>(W2, W2t, HC1, HC2, HC1);
  }

  // layer 1
  {
    dim3 grid(HC1 / 128, Mpad / 128);  // N-tile fastest
    mfma_gemm_kernel<unsigned short><<<grid, 256, 0, stream>>>(xb, W1t, hb, Nn, HC1, K1pad);
  }
  att_coef_kernel<<<(Nn + 3) / 4, 256, 0, stream>>>(hb, att_src1, att_dst1, a_s, a_d, Nn, H, C1);
  edge_softmax_kernel<<<(Nn * H + TB - 1) / TB, TB, 0, stream>>>(a_s, a_d, offs, srcs, alpha, Nn, H);
  aggregate1_kernel<<<Nn, 320, 0, stream>>>(hb, alpha, offs, srcs, b1, xb2, H, C1, HC1);

  // layer 2
  {
    dim3 grid(HC2 / 128, Mpad / 128);
    mfma_gemm_kernel<unsigned short><<<grid, 256, 0, stream>>>(xb2, W2t, hb, Nn, HC2, HC1);
  }
  att_coef_kernel<<<(Nn + 3) / 4, 256, 0, stream>>>(hb, att_src2, att_dst2, a_s, a_d, Nn, H, C2);
  edge_softmax_kernel<<<(Nn * H + TB - 1) / TB, TB, 0, stream>>>(a_s, a_d, offs, srcs, alpha, Nn, H);
  aggregate2_kernel<<<Nn, 256, 0, stream>>>(hb, alpha, offs, srcs, b2, out, H, C2);
}